// Round 8
// baseline (433.569 us; speedup 1.0000x reference)
//
#include <hip/hip_runtime.h>
#include <cstdint>
#include <cstddef>

#define N_NODES_C  50000
#define N_EDGES_C  800000
#define IN_F_C     256
#define HID_C      128
#define N_GRAPHS_C 256
#define NEG_SLOPE_C 0.2f
#define SCAN_NB    ((N_NODES_C + 255) / 256)   // 196 blocks
#define POOL_SPLIT 8
#define SCAT_BUCKETS 8
#define SCAT_CHUNKS  256

typedef _Float16 f16x8 __attribute__((ext_vector_type(8)));
typedef float    f32x4 __attribute__((ext_vector_type(4)));

// ---------------------------------------------------------------------------
// CSR build: histogram (+per-edge rank) -> hierarchical scan -> atomic-free
// bucketed scatter.
// ---------------------------------------------------------------------------
__global__ void hist_rank_kernel(const int* __restrict__ dst, int* __restrict__ deg,
                                 int* __restrict__ rank, int E) {
    int e = blockIdx.x * blockDim.x + threadIdx.x;
    if (e < E) rank[e] = atomicAdd(&deg[dst[e]], 1);
}

// Per-block sums of deg (coalesced), 256 elems/block.
__global__ __launch_bounds__(256) void scan1_kernel(const int* __restrict__ deg,
                                                    int* __restrict__ bsum, int n) {
    int i = blockIdx.x * 256 + threadIdx.x;
    int lane = threadIdx.x & 63;
    int w = threadIdx.x >> 6;
    int v = (i < n) ? deg[i] : 0;
    #pragma unroll
    for (int off = 32; off >= 1; off >>= 1) v += __shfl_xor(v, off);
    __shared__ int ws_[4];
    if (lane == 0) ws_[w] = v;
    __syncthreads();
    if (threadIdx.x == 0) bsum[blockIdx.x] = ws_[0] + ws_[1] + ws_[2] + ws_[3];
}

// Exclusive scan of the block sums (nb <= 256), single block.
__global__ __launch_bounds__(256) void scan2_kernel(int* __restrict__ bsum, int nb) {
    int t = threadIdx.x;
    int lane = t & 63;
    int w = t >> 6;
    int orig = (t < nb) ? bsum[t] : 0;
    int v = orig;
    #pragma unroll
    for (int off = 1; off < 64; off <<= 1) {
        int u = __shfl_up(v, off);
        if (lane >= off) v += u;
    }
    __shared__ int wsum[4];
    if (lane == 63) wsum[w] = v;
    __syncthreads();
    int add = 0;
    for (int i = 0; i < w; ++i) add += wsum[i];
    if (t < nb) bsum[t] = v + add - orig;   // exclusive prefix
}

// Block-local exclusive scan + block offset -> row_start.
__global__ __launch_bounds__(256) void scan3_kernel(const int* __restrict__ deg,
                                                    const int* __restrict__ boff,
                                                    int* __restrict__ row_start, int n) {
    int i = blockIdx.x * 256 + threadIdx.x;
    int lane = threadIdx.x & 63;
    int w = threadIdx.x >> 6;
    int d = (i < n) ? deg[i] : 0;
    int v = d;
    #pragma unroll
    for (int off = 1; off < 64; off <<= 1) {
        int u = __shfl_up(v, off);
        if (lane >= off) v += u;
    }
    __shared__ int wsum[4];
    if (lane == 63) wsum[w] = v;
    __syncthreads();
    int add = boff[blockIdx.x];
    for (int k = 0; k < w; ++k) add += wsum[k];
    int excl = v - d + add;
    if (i < n) {
        row_start[i] = excl;
        if (i == n - 1) row_start[n] = excl + d;
    }
}

// Atomic-free bucketed scatter (bucket rides round-robin block->XCD mapping).
__global__ __launch_bounds__(256) void scatter_bucket_kernel(
    const int* __restrict__ src, const int* __restrict__ dst,
    const int* __restrict__ rank, const int* __restrict__ row_start,
    int* __restrict__ csr_src, int E)
{
    const int bucket = blockIdx.x & (SCAT_BUCKETS - 1);
    const int chunk  = blockIdx.x / SCAT_BUCKETS;
    constexpr int NPB = (N_NODES_C + SCAT_BUCKETS - 1) / SCAT_BUCKETS;  // 6250
    const int lo = bucket * NPB;
    const int hi = min(lo + NPB, N_NODES_C);
    const int per = (E + SCAT_CHUNKS - 1) / SCAT_CHUNKS;
    const int e0 = chunk * per;
    const int e1 = min(e0 + per, E);
    for (int e = e0 + (int)threadIdx.x; e < e1; e += 256) {
        int d = dst[e];
        if (d >= lo && d < hi) {
            csr_src[row_start[d] + rank[e]] = src[e];
        }
    }
}

// ---------------------------------------------------------------------------
// One-time W conversion: W[K][128] fp32 -> WT_hi/WT_lo [128][K] f16 (Markidis
// split). Transposed so B fragments read 8 contiguous k-values per lane.
// ---------------------------------------------------------------------------
__global__ void convert_w_kernel(const float* __restrict__ W,
                                 _Float16* __restrict__ wt_hi,
                                 _Float16* __restrict__ wt_lo, int K) {
    int id = blockIdx.x * 256 + threadIdx.x;
    if (id >= K * 128) return;
    int c = id & 127;
    int k = id >> 7;
    float w = W[(size_t)k * 128 + c];
    _Float16 h = (_Float16)w;
    _Float16 l = (_Float16)(w - (float)h);
    wt_hi[(size_t)c * K + k] = h;
    wt_lo[(size_t)c * K + k] = l;
}

// ---------------------------------------------------------------------------
// MFMA GEMM: H[n,128] = act(X)[n,K] @ W[K,128], f16 split (hi*hi+hi*lo+lo*hi),
// mfma_f32_16x16x32_f16. H written f16-only (gather path). Fused alpha dots.
// ---------------------------------------------------------------------------
template <int K, bool RELU>
__global__ __launch_bounds__(256) void gemm_mfma_kernel(
    const float* __restrict__ X,
    const _Float16* __restrict__ WTh, const _Float16* __restrict__ WTl,
    const float* __restrict__ a_src, const float* __restrict__ a_dst,
    _Float16* __restrict__ Hh, float* __restrict__ alpha_s, float* __restrict__ alpha_d,
    int n_rows)
{
    constexpr int NS = K / 32;
    __shared__ _Float16 XsH[2][64 * 32];   // 2 x 4 KiB
    __shared__ _Float16 XsL[2][64 * 32];   // 2 x 4 KiB
    __shared__ float aps[4][64];           // 1 KiB
    __shared__ float apd[4][64];           // 1 KiB

    const int t = threadIdx.x;
    const int row0 = blockIdx.x * 64;
    const int lane = t & 63;
    const int wv = t >> 6;        // wave id 0..3
    const int l15 = lane & 15;
    const int l4 = lane >> 4;     // 0..3
    const int wcol = wv * 32;

    const int sr = t >> 2;        // 0..63
    const int skg = t & 3;        // 0..3
    const int sgrow = row0 + sr;
    const int sslot = skg ^ (sr & 3);
    const int sldsoff = sr * 32 + sslot * 8;
    const bool srow_ok = (sgrow < n_rows);
    const float* __restrict__ srowp = X + (size_t)sgrow * K + skg * 8;

    f32x4 acc[4][2];
    #pragma unroll
    for (int mt = 0; mt < 4; ++mt)
        #pragma unroll
        for (int nt = 0; nt < 2; ++nt)
            acc[mt][nt] = (f32x4){0.f, 0.f, 0.f, 0.f};

    // --- prologue: stage step 0 ---
    {
        float4 xa = make_float4(0.f, 0.f, 0.f, 0.f), xb = xa;
        if (srow_ok) {
            xa = *reinterpret_cast<const float4*>(srowp);
            xb = *reinterpret_cast<const float4*>(srowp + 4);
        }
        float v[8] = {xa.x, xa.y, xa.z, xa.w, xb.x, xb.y, xb.z, xb.w};
        f16x8 hi, lo;
        #pragma unroll
        for (int i = 0; i < 8; ++i) {
            float x = v[i];
            if (RELU) x = fmaxf(x, 0.f);
            _Float16 h = (_Float16)x;
            hi[i] = h;
            lo[i] = (_Float16)(x - (float)h);
        }
        *reinterpret_cast<f16x8*>(&XsH[0][sldsoff]) = hi;
        *reinterpret_cast<f16x8*>(&XsL[0][sldsoff]) = lo;
    }
    __syncthreads();

    int cur = 0;
    for (int step = 0; step < NS; ++step) {
        const int k0 = step * 32;
        float4 nxa = make_float4(0.f, 0.f, 0.f, 0.f), nxb = nxa;
        const bool hasNext = (step + 1 < NS);
        if (hasNext && srow_ok) {
            nxa = *reinterpret_cast<const float4*>(srowp + k0 + 32);
            nxb = *reinterpret_cast<const float4*>(srowp + k0 + 36);
        }
        f16x8 bh[2], bl[2];
        #pragma unroll
        for (int nt = 0; nt < 2; ++nt) {
            const size_t bo = (size_t)(wcol + nt * 16 + l15) * K + k0 + l4 * 8;
            bh[nt] = *reinterpret_cast<const f16x8*>(WTh + bo);
            bl[nt] = *reinterpret_cast<const f16x8*>(WTl + bo);
        }
        const int aslot = l4 ^ (l15 & 3);
        f16x8 ah[4], al[4];
        #pragma unroll
        for (int mt = 0; mt < 4; ++mt) {
            const int off = (mt * 16 + l15) * 32 + aslot * 8;
            ah[mt] = *reinterpret_cast<const f16x8*>(&XsH[cur][off]);
            al[mt] = *reinterpret_cast<const f16x8*>(&XsL[cur][off]);
        }
        #pragma unroll
        for (int mt = 0; mt < 4; ++mt)
            #pragma unroll
            for (int nt = 0; nt < 2; ++nt) {
                acc[mt][nt] = __builtin_amdgcn_mfma_f32_16x16x32_f16(ah[mt], bh[nt], acc[mt][nt], 0, 0, 0);
                acc[mt][nt] = __builtin_amdgcn_mfma_f32_16x16x32_f16(ah[mt], bl[nt], acc[mt][nt], 0, 0, 0);
                acc[mt][nt] = __builtin_amdgcn_mfma_f32_16x16x32_f16(al[mt], bh[nt], acc[mt][nt], 0, 0, 0);
            }
        if (hasNext) {
            float v[8] = {nxa.x, nxa.y, nxa.z, nxa.w, nxb.x, nxb.y, nxb.z, nxb.w};
            f16x8 hi, lo;
            #pragma unroll
            for (int i = 0; i < 8; ++i) {
                float x = v[i];
                if (RELU) x = fmaxf(x, 0.f);
                _Float16 h = (_Float16)x;
                hi[i] = h;
                lo[i] = (_Float16)(x - (float)h);
            }
            *reinterpret_cast<f16x8*>(&XsH[cur ^ 1][sldsoff]) = hi;
            *reinterpret_cast<f16x8*>(&XsL[cur ^ 1][sldsoff]) = lo;
        }
        __syncthreads();
        cur ^= 1;
    }

    // --- epilogue: f16 H stores + fused alpha dots (f32) ---
    const float as0 = a_src[wcol + l15];
    const float as1 = a_src[wcol + 16 + l15];
    const float ad0 = a_dst[wcol + l15];
    const float ad1 = a_dst[wcol + 16 + l15];

    #pragma unroll
    for (int mt = 0; mt < 4; ++mt) {
        #pragma unroll
        for (int reg = 0; reg < 4; ++reg) {
            const int lrow = mt * 16 + l4 * 4 + reg;
            const int grow = row0 + lrow;
            if (grow < n_rows) {
                Hh[(size_t)grow * 128 + wcol + l15]      = (_Float16)acc[mt][0][reg];
                Hh[(size_t)grow * 128 + wcol + 16 + l15] = (_Float16)acc[mt][1][reg];
            }
            float s = acc[mt][0][reg] * as0 + acc[mt][1][reg] * as1;
            float d = acc[mt][0][reg] * ad0 + acc[mt][1][reg] * ad1;
            #pragma unroll
            for (int off = 8; off >= 1; off >>= 1) {
                s += __shfl_xor(s, off);
                d += __shfl_xor(d, off);
            }
            if (l15 == 0) {
                aps[wv][lrow] = s;
                apd[wv][lrow] = d;
            }
        }
    }
    __syncthreads();
    if (t < 64) {
        const int grow = row0 + t;
        if (grow < n_rows)
            alpha_s[grow] = aps[0][t] + aps[1][t] + aps[2][t] + aps[3][t];
    } else if (t < 128) {
        const int tt = t - 64;
        const int grow = row0 + tt;
        if (grow < n_rows)
            alpha_d[grow] = apd[0][tt] + apd[1][tt] + apd[2][tt] + apd[3][tt];
    }
}

// ---------------------------------------------------------------------------
// Per-dst-node softmax + weighted aggregation, v5: FOUR nodes per wave.
// R7 diagnosis: v4 (2 nodes, 8 gathers in flight) = 41 us @ 32% HBM / 39%
// VALU -> still memory-parallelism-bound. v5 fuses 4 contiguous nodes:
// 4 independent softmax chains + 16 independent dwordx4 row-fetches per
// gather iteration. All indices compile-time (full unroll) to stay in VGPRs.
// Out-of-range slots broadcast s=0 -> row 0 (cache-hot), no extra HBM.
// ---------------------------------------------------------------------------
__global__ __launch_bounds__(256) void aggregate_kernel(
    const _Float16* __restrict__ Hh, const float* __restrict__ alpha_s,
    const float* __restrict__ alpha_d, const int* __restrict__ row_start,
    const int* __restrict__ csr_src, const float* __restrict__ bias,
    float* __restrict__ OUT, int n_nodes)
{
    int wvid = (blockIdx.x * blockDim.x + threadIdx.x) >> 6;
    int lane = threadIdx.x & 63;
    int n0 = wvid * 4;
    if (n0 >= n_nodes) return;

    const int grp = lane >> 4;           // slot group 0..3
    const int l16 = lane & 15;           // col block: cols 8*l16 .. 8*l16+7
    const _Float16* __restrict__ Hc = Hh + l16 * 8;

    // contiguous rows: 5 row_start reads cover 4 nodes
    int rs[5];
    #pragma unroll
    for (int k = 0; k < 5; ++k) {
        int idx = n0 + k;
        rs[k] = row_start[idx < n_nodes ? idx : n_nodes];
    }
    float ad[4];
    #pragma unroll
    for (int k = 0; k < 4; ++k)
        ad[k] = (n0 + k < n_nodes) ? alpha_d[n0 + k] : 0.f;

    float S[4];
    float acc[4][8];
    #pragma unroll
    for (int k = 0; k < 4; ++k) {
        S[k] = 0.f;
        #pragma unroll
        for (int q = 0; q < 8; ++q) acc[k][q] = 0.f;
    }

    int base[4];
    #pragma unroll
    for (int k = 0; k < 4; ++k) base[k] = rs[k];

    bool more = true;
    while (more) {
        int cnt[4];
        float w[4];
        int s[4];
        // 4 independent softmax chains (csr load -> alpha gather -> exp)
        #pragma unroll
        for (int k = 0; k < 4; ++k) {
            int rem = rs[k + 1] - base[k];
            cnt[k] = rem > 0 ? (rem < 64 ? rem : 64) : 0;
            float wk = 0.f;
            int sk = 0;
            if (lane < cnt[k]) {
                sk = csr_src[base[k] + lane];
                float z = alpha_s[sk] + ad[k];
                z = (z >= 0.f) ? z : NEG_SLOPE_C * z;
                wk = __expf(z);
            }
            w[k] = wk;
            s[k] = sk;
        }
        #pragma unroll
        for (int k = 0; k < 4; ++k) {
            float r = w[k];
            #pragma unroll
            for (int off = 32; off >= 1; off >>= 1) r += __shfl_xor(r, off);
            S[k] += r;
        }

        int cmax = max(max(cnt[0], cnt[1]), max(cnt[2], cnt[3]));
        for (int jj = 0; jj < cmax; jj += 16) {
            float bw[4][4];
            int bs[4][4];
            #pragma unroll
            for (int k = 0; k < 4; ++k) {
                #pragma unroll
                for (int t = 0; t < 4; ++t) {
                    int idx = jj + t * 4 + grp;
                    float ww = __shfl(w[k], idx & 63);
                    int ss = __shfl(s[k], idx & 63);
                    bw[k][t] = (idx < cnt[k]) ? ww : 0.f;
                    bs[k][t] = ss;
                }
            }
            // 16 independent row-fetches in flight
            f16x8 h[4][4];
            #pragma unroll
            for (int k = 0; k < 4; ++k)
                #pragma unroll
                for (int t = 0; t < 4; ++t)
                    h[k][t] = *reinterpret_cast<const f16x8*>(Hc + (size_t)bs[k][t] * 128);
            #pragma unroll
            for (int k = 0; k < 4; ++k)
                #pragma unroll
                for (int t = 0; t < 4; ++t)
                    #pragma unroll
                    for (int q = 0; q < 8; ++q)
                        acc[k][q] = fmaf(bw[k][t], (float)h[k][t][q], acc[k][q]);
        }
        #pragma unroll
        for (int k = 0; k < 4; ++k) base[k] += 64;
        more = false;
        #pragma unroll
        for (int k = 0; k < 4; ++k) more = more || (base[k] < rs[k + 1]);
    }

    // Reduce across the 4 groups, store per node.
    #pragma unroll
    for (int k = 0; k < 4; ++k) {
        #pragma unroll
        for (int q = 0; q < 8; ++q) {
            acc[k][q] += __shfl_xor(acc[k][q], 16);
            acc[k][q] += __shfl_xor(acc[k][q], 32);
        }
    }

    if (grp == 0) {
        float4 b0 = *reinterpret_cast<const float4*>(bias + l16 * 8);
        float4 b1 = *reinterpret_cast<const float4*>(bias + l16 * 8 + 4);
        #pragma unroll
        for (int k = 0; k < 4; ++k) {
            int node = n0 + k;
            if (node < n_nodes) {
                float inv = (rs[k + 1] > rs[k]) ? (1.f / S[k]) : 0.f;
                float4 o0, o1;
                o0.x = acc[k][0] * inv + b0.x;
                o0.y = acc[k][1] * inv + b0.y;
                o0.z = acc[k][2] * inv + b0.z;
                o0.w = acc[k][3] * inv + b0.w;
                o1.x = acc[k][4] * inv + b1.x;
                o1.y = acc[k][5] * inv + b1.y;
                o1.z = acc[k][6] * inv + b1.z;
                o1.w = acc[k][7] * inv + b1.w;
                *reinterpret_cast<float4*>(OUT + (size_t)node * 128 + l16 * 8)     = o0;
                *reinterpret_cast<float4*>(OUT + (size_t)node * 128 + l16 * 8 + 4) = o1;
            }
        }
    }
}

// ---------------------------------------------------------------------------
// Per-graph node ranges via binary search on sorted batch
// ---------------------------------------------------------------------------
__global__ void graph_ranges_kernel(const int* __restrict__ batch, int n_nodes,
                                    int n_graphs, int* __restrict__ gstart) {
    int g = blockIdx.x * blockDim.x + threadIdx.x;
    if (g > n_graphs) return;
    int lo = 0, hi = n_nodes;
    while (lo < hi) {
        int mid = (lo + hi) >> 1;
        if (batch[mid] < g) lo = mid + 1; else hi = mid;
    }
    gstart[g] = lo;
}

// ---------------------------------------------------------------------------
// Mean pool, stage A: 2048 blocks (16 waves/CU), disjoint chunk sums.
// ---------------------------------------------------------------------------
__global__ __launch_bounds__(128) void pool_partial_kernel(
    const float* __restrict__ X, const int* __restrict__ gstart,
    float* __restrict__ partial)
{
    int g = blockIdx.x >> 3;           // POOL_SPLIT = 8
    int split = blockIdx.x & 7;
    int c = threadIdx.x;               // 0..127
    int s = gstart[g], e = gstart[g + 1];
    int len = e - s;
    int i0 = s + (len * split) / POOL_SPLIT;
    int i1 = s + (len * (split + 1)) / POOL_SPLIT;
    float acc = 0.f;
    for (int i = i0; i < i1; ++i) acc += X[(size_t)i * 128 + c];
    partial[(size_t)blockIdx.x * 128 + c] = acc;
}

// ---------------------------------------------------------------------------
// Mean pool stage B + final linear [128 -> 8].
// ---------------------------------------------------------------------------
__global__ __launch_bounds__(128) void pool_final_kernel(
    const float* __restrict__ partial, const int* __restrict__ gstart,
    const float* __restrict__ lin_w, const float* __restrict__ lin_b,
    float* __restrict__ out)
{
    int g = blockIdx.x;
    int c = threadIdx.x;   // 0..127
    float acc = 0.f;
    #pragma unroll
    for (int sp = 0; sp < POOL_SPLIT; ++sp)
        acc += partial[(size_t)(g * POOL_SPLIT + sp) * 128 + c];
    float cnt = (float)(gstart[g + 1] - gstart[g]);
    float pooled = acc / fmaxf(cnt, 1.0f);
    __shared__ float p[128];
    p[c] = pooled;
    __syncthreads();
    if (c < 8) {
        float o = lin_b[c];
        for (int k = 0; k < 128; ++k) o += p[k] * lin_w[k * 8 + c];
        out[g * 8 + c] = o;
    }
}

// ---------------------------------------------------------------------------
extern "C" void kernel_launch(void* const* d_in, const int* in_sizes, int n_in,
                              void* d_out, int out_size, void* d_ws, size_t ws_size,
                              hipStream_t stream)
{
    const float* x     = (const float*)d_in[0];
    const int*   ei    = (const int*)d_in[1];
    // d_in[2] = edge_attr (unused)
    const int*   batch = (const int*)d_in[3];
    const float* W[3]   = {(const float*)d_in[4],  (const float*)d_in[8],  (const float*)d_in[12]};
    const float* asr[3] = {(const float*)d_in[5],  (const float*)d_in[9],  (const float*)d_in[13]};
    const float* adt[3] = {(const float*)d_in[6],  (const float*)d_in[10], (const float*)d_in[14]};
    const float* bia[3] = {(const float*)d_in[7],  (const float*)d_in[11], (const float*)d_in[15]};
    const float* lin_w = (const float*)d_in[16];
    const float* lin_b = (const float*)d_in[17];
    float* out = (float*)d_out;

    // workspace carve-up
    char* ws = (char*)d_ws;
    size_t off = 0;
    auto carve = [&](size_t bytes) {
        void* p = ws + off;
        off = (off + bytes + 255) & ~(size_t)255;
        return p;
    };
    _Float16* Hh    = (_Float16*)carve((size_t)N_NODES_C * 128 * 2);  // f16 H (gather path)
    float* bufB     = (float*)carve((size_t)N_NODES_C * 128 * 4);     // layer out / next x
    float* alpha_s  = (float*)carve((size_t)N_NODES_C * 4);
    float* alpha_d  = (float*)carve((size_t)N_NODES_C * 4);
    int*   deg      = (int*)carve((size_t)N_NODES_C * 4);
    int*   row_start= (int*)carve((size_t)(N_NODES_C + 1) * 4);
    int*   rank     = (int*)carve((size_t)N_EDGES_C * 4);
    int*   csr_src  = (int*)carve((size_t)N_EDGES_C * 4);
    int*   gstart   = (int*)carve((size_t)(N_GRAPHS_C + 1) * 4);
    int*   bsum     = (int*)carve((size_t)SCAN_NB * 4);
    float* ppart    = (float*)carve((size_t)N_GRAPHS_C * POOL_SPLIT * 128 * 4);
    _Float16* wt_h[3];
    _Float16* wt_l[3];
    wt_h[0] = (_Float16*)carve((size_t)128 * 256 * 2);
    wt_l[0] = (_Float16*)carve((size_t)128 * 256 * 2);
    wt_h[1] = (_Float16*)carve((size_t)128 * 128 * 2);
    wt_l[1] = (_Float16*)carve((size_t)128 * 128 * 2);
    wt_h[2] = (_Float16*)carve((size_t)128 * 128 * 2);
    wt_l[2] = (_Float16*)carve((size_t)128 * 128 * 2);

    const int* src = ei;             // edge_index[0]
    const int* dst = ei + N_EDGES_C; // edge_index[1]

    // --- CSR build (graph is identical across layers) + W conversion ---
    hipMemsetAsync(deg, 0, (size_t)N_NODES_C * 4, stream);
    hist_rank_kernel<<<(N_EDGES_C + 255) / 256, 256, 0, stream>>>(dst, deg, rank, N_EDGES_C);
    scan1_kernel<<<SCAN_NB, 256, 0, stream>>>(deg, bsum, N_NODES_C);
    scan2_kernel<<<1, 256, 0, stream>>>(bsum, SCAN_NB);
    scan3_kernel<<<SCAN_NB, 256, 0, stream>>>(deg, bsum, row_start, N_NODES_C);
    scatter_bucket_kernel<<<SCAT_BUCKETS * SCAT_CHUNKS, 256, 0, stream>>>(
        src, dst, rank, row_start, csr_src, N_EDGES_C);
    graph_ranges_kernel<<<2, 256, 0, stream>>>(batch, N_NODES_C, N_GRAPHS_C, gstart);
    convert_w_kernel<<<(256 * 128 + 255) / 256, 256, 0, stream>>>(W[0], wt_h[0], wt_l[0], 256);
    convert_w_kernel<<<(128 * 128 + 255) / 256, 256, 0, stream>>>(W[1], wt_h[1], wt_l[1], 128);
    convert_w_kernel<<<(128 * 128 + 255) / 256, 256, 0, stream>>>(W[2], wt_h[2], wt_l[2], 128);

    const int gemm_grid = (N_NODES_C + 63) / 64;
    const int agg_grid  = (N_NODES_C + 15) / 16;   // 4 nodes/wave, 4 waves/block

    // --- layer 0 (K=256, no input relu) ---
    gemm_mfma_kernel<IN_F_C, false><<<gemm_grid, 256, 0, stream>>>(
        x, wt_h[0], wt_l[0], asr[0], adt[0], Hh, alpha_s, alpha_d, N_NODES_C);
    aggregate_kernel<<<agg_grid, 256, 0, stream>>>(
        Hh, alpha_s, alpha_d, row_start, csr_src, bia[0], bufB, N_NODES_C);

    // --- layer 1 (K=128, relu on input) ---
    gemm_mfma_kernel<HID_C, true><<<gemm_grid, 256, 0, stream>>>(
        bufB, wt_h[1], wt_l[1], asr[1], adt[1], Hh, alpha_s, alpha_d, N_NODES_C);
    aggregate_kernel<<<agg_grid, 256, 0, stream>>>(
        Hh, alpha_s, alpha_d, row_start, csr_src, bia[1], bufB, N_NODES_C);

    // --- layer 2 (K=128, relu on input, no relu on output) ---
    gemm_mfma_kernel<HID_C, true><<<gemm_grid, 256, 0, stream>>>(
        bufB, wt_h[2], wt_l[2], asr[2], adt[2], Hh, alpha_s, alpha_d, N_NODES_C);
    aggregate_kernel<<<agg_grid, 256, 0, stream>>>(
        Hh, alpha_s, alpha_d, row_start, csr_src, bia[2], bufB, N_NODES_C);

    // --- mean pool (2-stage) + linear ---
    pool_partial_kernel<<<N_GRAPHS_C * POOL_SPLIT, 128, 0, stream>>>(bufB, gstart, ppart);
    pool_final_kernel<<<N_GRAPHS_C, 128, 0, stream>>>(ppart, gstart, lin_w, lin_b, out);
}

// Round 9
// 394.750 us; speedup vs baseline: 1.0983x; 1.0983x over previous
//
#include <hip/hip_runtime.h>
#include <cstdint>
#include <cstddef>

#define N_NODES_C  50000
#define N_EDGES_C  800000
#define IN_F_C     256
#define HID_C      128
#define N_GRAPHS_C 256
#define NEG_SLOPE_C 0.2f
#define SCAN_NB    ((N_NODES_C + 255) / 256)   // 196 blocks
#define POOL_SPLIT 8
#define SCAT_BUCKETS 8
#define SCAT_CHUNKS  256

typedef _Float16 f16x8 __attribute__((ext_vector_type(8)));
typedef float    f32x4 __attribute__((ext_vector_type(4)));

// ---------------------------------------------------------------------------
// CSR build: histogram (+per-edge rank) -> hierarchical scan -> atomic-free
// bucketed scatter.
// ---------------------------------------------------------------------------
__global__ void hist_rank_kernel(const int* __restrict__ dst, int* __restrict__ deg,
                                 int* __restrict__ rank, int E) {
    int e = blockIdx.x * blockDim.x + threadIdx.x;
    if (e < E) rank[e] = atomicAdd(&deg[dst[e]], 1);
}

// Per-block sums of deg (coalesced), 256 elems/block.
__global__ __launch_bounds__(256) void scan1_kernel(const int* __restrict__ deg,
                                                    int* __restrict__ bsum, int n) {
    int i = blockIdx.x * 256 + threadIdx.x;
    int lane = threadIdx.x & 63;
    int w = threadIdx.x >> 6;
    int v = (i < n) ? deg[i] : 0;
    #pragma unroll
    for (int off = 32; off >= 1; off >>= 1) v += __shfl_xor(v, off);
    __shared__ int ws_[4];
    if (lane == 0) ws_[w] = v;
    __syncthreads();
    if (threadIdx.x == 0) bsum[blockIdx.x] = ws_[0] + ws_[1] + ws_[2] + ws_[3];
}

// Exclusive scan of the block sums (nb <= 256), single block.
__global__ __launch_bounds__(256) void scan2_kernel(int* __restrict__ bsum, int nb) {
    int t = threadIdx.x;
    int lane = t & 63;
    int w = t >> 6;
    int orig = (t < nb) ? bsum[t] : 0;
    int v = orig;
    #pragma unroll
    for (int off = 1; off < 64; off <<= 1) {
        int u = __shfl_up(v, off);
        if (lane >= off) v += u;
    }
    __shared__ int wsum[4];
    if (lane == 63) wsum[w] = v;
    __syncthreads();
    int add = 0;
    for (int i = 0; i < w; ++i) add += wsum[i];
    if (t < nb) bsum[t] = v + add - orig;   // exclusive prefix
}

// Block-local exclusive scan + block offset -> row_start.
__global__ __launch_bounds__(256) void scan3_kernel(const int* __restrict__ deg,
                                                    const int* __restrict__ boff,
                                                    int* __restrict__ row_start, int n) {
    int i = blockIdx.x * 256 + threadIdx.x;
    int lane = threadIdx.x & 63;
    int w = threadIdx.x >> 6;
    int d = (i < n) ? deg[i] : 0;
    int v = d;
    #pragma unroll
    for (int off = 1; off < 64; off <<= 1) {
        int u = __shfl_up(v, off);
        if (lane >= off) v += u;
    }
    __shared__ int wsum[4];
    if (lane == 63) wsum[w] = v;
    __syncthreads();
    int add = boff[blockIdx.x];
    for (int k = 0; k < w; ++k) add += wsum[k];
    int excl = v - d + add;
    if (i < n) {
        row_start[i] = excl;
        if (i == n - 1) row_start[n] = excl + d;
    }
}

// Atomic-free bucketed scatter (bucket rides round-robin block->XCD mapping).
__global__ __launch_bounds__(256) void scatter_bucket_kernel(
    const int* __restrict__ src, const int* __restrict__ dst,
    const int* __restrict__ rank, const int* __restrict__ row_start,
    int* __restrict__ csr_src, int E)
{
    const int bucket = blockIdx.x & (SCAT_BUCKETS - 1);
    const int chunk  = blockIdx.x / SCAT_BUCKETS;
    constexpr int NPB = (N_NODES_C + SCAT_BUCKETS - 1) / SCAT_BUCKETS;  // 6250
    const int lo = bucket * NPB;
    const int hi = min(lo + NPB, N_NODES_C);
    const int per = (E + SCAT_CHUNKS - 1) / SCAT_CHUNKS;
    const int e0 = chunk * per;
    const int e1 = min(e0 + per, E);
    for (int e = e0 + (int)threadIdx.x; e < e1; e += 256) {
        int d = dst[e];
        if (d >= lo && d < hi) {
            csr_src[row_start[d] + rank[e]] = src[e];
        }
    }
}

// ---------------------------------------------------------------------------
// One-time W conversion: W[K][128] fp32 -> WT_hi/WT_lo [128][K] f16 (Markidis
// split). Transposed so B fragments read 8 contiguous k-values per lane.
// ---------------------------------------------------------------------------
__global__ void convert_w_kernel(const float* __restrict__ W,
                                 _Float16* __restrict__ wt_hi,
                                 _Float16* __restrict__ wt_lo, int K) {
    int id = blockIdx.x * 256 + threadIdx.x;
    if (id >= K * 128) return;
    int c = id & 127;
    int k = id >> 7;
    float w = W[(size_t)k * 128 + c];
    _Float16 h = (_Float16)w;
    _Float16 l = (_Float16)(w - (float)h);
    wt_hi[(size_t)c * K + k] = h;
    wt_lo[(size_t)c * K + k] = l;
}

// ---------------------------------------------------------------------------
// MFMA GEMM: H[n,128] = act(X)[n,K] @ W[K,128], f16 split (hi*hi+hi*lo+lo*hi),
// mfma_f32_16x16x32_f16. H written f16-only (gather path). Fused alpha dots.
// ---------------------------------------------------------------------------
template <int K, bool RELU>
__global__ __launch_bounds__(256) void gemm_mfma_kernel(
    const float* __restrict__ X,
    const _Float16* __restrict__ WTh, const _Float16* __restrict__ WTl,
    const float* __restrict__ a_src, const float* __restrict__ a_dst,
    _Float16* __restrict__ Hh, float* __restrict__ alpha_s, float* __restrict__ alpha_d,
    int n_rows)
{
    constexpr int NS = K / 32;
    __shared__ _Float16 XsH[2][64 * 32];   // 2 x 4 KiB
    __shared__ _Float16 XsL[2][64 * 32];   // 2 x 4 KiB
    __shared__ float aps[4][64];           // 1 KiB
    __shared__ float apd[4][64];           // 1 KiB

    const int t = threadIdx.x;
    const int row0 = blockIdx.x * 64;
    const int lane = t & 63;
    const int wv = t >> 6;        // wave id 0..3
    const int l15 = lane & 15;
    const int l4 = lane >> 4;     // 0..3
    const int wcol = wv * 32;

    const int sr = t >> 2;        // 0..63
    const int skg = t & 3;        // 0..3
    const int sgrow = row0 + sr;
    const int sslot = skg ^ (sr & 3);
    const int sldsoff = sr * 32 + sslot * 8;
    const bool srow_ok = (sgrow < n_rows);
    const float* __restrict__ srowp = X + (size_t)sgrow * K + skg * 8;

    f32x4 acc[4][2];
    #pragma unroll
    for (int mt = 0; mt < 4; ++mt)
        #pragma unroll
        for (int nt = 0; nt < 2; ++nt)
            acc[mt][nt] = (f32x4){0.f, 0.f, 0.f, 0.f};

    // --- prologue: stage step 0 ---
    {
        float4 xa = make_float4(0.f, 0.f, 0.f, 0.f), xb = xa;
        if (srow_ok) {
            xa = *reinterpret_cast<const float4*>(srowp);
            xb = *reinterpret_cast<const float4*>(srowp + 4);
        }
        float v[8] = {xa.x, xa.y, xa.z, xa.w, xb.x, xb.y, xb.z, xb.w};
        f16x8 hi, lo;
        #pragma unroll
        for (int i = 0; i < 8; ++i) {
            float x = v[i];
            if (RELU) x = fmaxf(x, 0.f);
            _Float16 h = (_Float16)x;
            hi[i] = h;
            lo[i] = (_Float16)(x - (float)h);
        }
        *reinterpret_cast<f16x8*>(&XsH[0][sldsoff]) = hi;
        *reinterpret_cast<f16x8*>(&XsL[0][sldsoff]) = lo;
    }
    __syncthreads();

    int cur = 0;
    for (int step = 0; step < NS; ++step) {
        const int k0 = step * 32;
        float4 nxa = make_float4(0.f, 0.f, 0.f, 0.f), nxb = nxa;
        const bool hasNext = (step + 1 < NS);
        if (hasNext && srow_ok) {
            nxa = *reinterpret_cast<const float4*>(srowp + k0 + 32);
            nxb = *reinterpret_cast<const float4*>(srowp + k0 + 36);
        }
        f16x8 bh[2], bl[2];
        #pragma unroll
        for (int nt = 0; nt < 2; ++nt) {
            const size_t bo = (size_t)(wcol + nt * 16 + l15) * K + k0 + l4 * 8;
            bh[nt] = *reinterpret_cast<const f16x8*>(WTh + bo);
            bl[nt] = *reinterpret_cast<const f16x8*>(WTl + bo);
        }
        const int aslot = l4 ^ (l15 & 3);
        f16x8 ah[4], al[4];
        #pragma unroll
        for (int mt = 0; mt < 4; ++mt) {
            const int off = (mt * 16 + l15) * 32 + aslot * 8;
            ah[mt] = *reinterpret_cast<const f16x8*>(&XsH[cur][off]);
            al[mt] = *reinterpret_cast<const f16x8*>(&XsL[cur][off]);
        }
        #pragma unroll
        for (int mt = 0; mt < 4; ++mt)
            #pragma unroll
            for (int nt = 0; nt < 2; ++nt) {
                acc[mt][nt] = __builtin_amdgcn_mfma_f32_16x16x32_f16(ah[mt], bh[nt], acc[mt][nt], 0, 0, 0);
                acc[mt][nt] = __builtin_amdgcn_mfma_f32_16x16x32_f16(ah[mt], bl[nt], acc[mt][nt], 0, 0, 0);
                acc[mt][nt] = __builtin_amdgcn_mfma_f32_16x16x32_f16(al[mt], bh[nt], acc[mt][nt], 0, 0, 0);
            }
        if (hasNext) {
            float v[8] = {nxa.x, nxa.y, nxa.z, nxa.w, nxb.x, nxb.y, nxb.z, nxb.w};
            f16x8 hi, lo;
            #pragma unroll
            for (int i = 0; i < 8; ++i) {
                float x = v[i];
                if (RELU) x = fmaxf(x, 0.f);
                _Float16 h = (_Float16)x;
                hi[i] = h;
                lo[i] = (_Float16)(x - (float)h);
            }
            *reinterpret_cast<f16x8*>(&XsH[cur ^ 1][sldsoff]) = hi;
            *reinterpret_cast<f16x8*>(&XsL[cur ^ 1][sldsoff]) = lo;
        }
        __syncthreads();
        cur ^= 1;
    }

    // --- epilogue: f16 H stores + fused alpha dots (f32) ---
    const float as0 = a_src[wcol + l15];
    const float as1 = a_src[wcol + 16 + l15];
    const float ad0 = a_dst[wcol + l15];
    const float ad1 = a_dst[wcol + 16 + l15];

    #pragma unroll
    for (int mt = 0; mt < 4; ++mt) {
        #pragma unroll
        for (int reg = 0; reg < 4; ++reg) {
            const int lrow = mt * 16 + l4 * 4 + reg;
            const int grow = row0 + lrow;
            if (grow < n_rows) {
                Hh[(size_t)grow * 128 + wcol + l15]      = (_Float16)acc[mt][0][reg];
                Hh[(size_t)grow * 128 + wcol + 16 + l15] = (_Float16)acc[mt][1][reg];
            }
            float s = acc[mt][0][reg] * as0 + acc[mt][1][reg] * as1;
            float d = acc[mt][0][reg] * ad0 + acc[mt][1][reg] * ad1;
            #pragma unroll
            for (int off = 8; off >= 1; off >>= 1) {
                s += __shfl_xor(s, off);
                d += __shfl_xor(d, off);
            }
            if (l15 == 0) {
                aps[wv][lrow] = s;
                apd[wv][lrow] = d;
            }
        }
    }
    __syncthreads();
    if (t < 64) {
        const int grow = row0 + t;
        if (grow < n_rows)
            alpha_s[grow] = aps[0][t] + aps[1][t] + aps[2][t] + aps[3][t];
    } else if (t < 128) {
        const int tt = t - 64;
        const int grow = row0 + tt;
        if (grow < n_rows)
            alpha_d[grow] = apd[0][tt] + apd[1][tt] + apd[2][tt] + apd[3][tt];
    }
}

// ---------------------------------------------------------------------------
// Per-dst-node softmax + weighted aggregation, v4: TWO nodes per wave.
// (Reverted from v5: 4 nodes/wave raised VGPR to 124 -> occupancy 18.8%,
// and the 16-slot/node quantum wasted ~50% of gather slots; v4's 60 VGPR /
// 8-in-flight point is the empirical optimum of the MLP-vs-occupancy curve.)
// ---------------------------------------------------------------------------
__global__ __launch_bounds__(256) void aggregate_kernel(
    const _Float16* __restrict__ Hh, const float* __restrict__ alpha_s,
    const float* __restrict__ alpha_d, const int* __restrict__ row_start,
    const int* __restrict__ csr_src, const float* __restrict__ bias,
    float* __restrict__ OUT, int n_nodes)
{
    int wvid = (blockIdx.x * blockDim.x + threadIdx.x) >> 6;
    int lane = threadIdx.x & 63;
    int nA = wvid * 2;
    int nB = nA + 1;
    if (nA >= n_nodes) return;
    const bool hasB = (nB < n_nodes);

    int eA0 = row_start[nA], eA1 = row_start[nA + 1];
    int eB0 = 0, eB1 = 0;
    if (hasB) { eB0 = eA1; eB1 = row_start[nB + 1]; }   // rows are contiguous
    float adA = alpha_d[nA];
    float adB = hasB ? alpha_d[nB] : 0.f;

    const int grp = lane >> 4;           // slot group 0..3
    const int l16 = lane & 15;           // col block: cols 8*l16 .. 8*l16+7
    const _Float16* __restrict__ Hc = Hh + l16 * 8;

    float SA = 0.f, SB = 0.f;
    float accA[8], accB[8];
    #pragma unroll
    for (int q = 0; q < 8; ++q) { accA[q] = 0.f; accB[q] = 0.f; }

    int baseA = eA0, baseB = eB0;
    while (baseA < eA1 || baseB < eB1) {
        int remA = eA1 - baseA;
        int remB = eB1 - baseB;
        int cntA = remA > 0 ? (remA < 64 ? remA : 64) : 0;
        int cntB = remB > 0 ? (remB < 64 ? remB : 64) : 0;

        float wA = 0.f; int sA = 0;
        if (lane < cntA) {
            sA = csr_src[baseA + lane];
            float z = alpha_s[sA] + adA;
            z = (z >= 0.f) ? z : NEG_SLOPE_C * z;
            wA = __expf(z);
        }
        float wB = 0.f; int sB = 0;
        if (lane < cntB) {
            sB = csr_src[baseB + lane];
            float z = alpha_s[sB] + adB;
            z = (z >= 0.f) ? z : NEG_SLOPE_C * z;
            wB = __expf(z);
        }
        float rA = wA, rB = wB;
        #pragma unroll
        for (int off = 32; off >= 1; off >>= 1) {
            rA += __shfl_xor(rA, off);
            rB += __shfl_xor(rB, off);
        }
        SA += rA;
        SB += rB;

        int cmax = cntA > cntB ? cntA : cntB;
        for (int jj = 0; jj < cmax; jj += 16) {
            int i0 = jj + grp;
            int i1 = jj + 4 + grp;
            int i2 = jj + 8 + grp;
            int i3 = jj + 12 + grp;
            // broadcast weights + indices for 4 A-slots and 4 B-slots
            float a0w = __shfl(wA, i0 & 63); int a0s = __shfl(sA, i0 & 63);
            float a1w = __shfl(wA, i1 & 63); int a1s = __shfl(sA, i1 & 63);
            float a2w = __shfl(wA, i2 & 63); int a2s = __shfl(sA, i2 & 63);
            float a3w = __shfl(wA, i3 & 63); int a3s = __shfl(sA, i3 & 63);
            float b0w = __shfl(wB, i0 & 63); int b0s = __shfl(sB, i0 & 63);
            float b1w = __shfl(wB, i1 & 63); int b1s = __shfl(sB, i1 & 63);
            float b2w = __shfl(wB, i2 & 63); int b2s = __shfl(sB, i2 & 63);
            float b3w = __shfl(wB, i3 & 63); int b3s = __shfl(sB, i3 & 63);
            a0w = (i0 < cntA) ? a0w : 0.f;
            a1w = (i1 < cntA) ? a1w : 0.f;
            a2w = (i2 < cntA) ? a2w : 0.f;
            a3w = (i3 < cntA) ? a3w : 0.f;
            b0w = (i0 < cntB) ? b0w : 0.f;
            b1w = (i1 < cntB) ? b1w : 0.f;
            b2w = (i2 < cntB) ? b2w : 0.f;
            b3w = (i3 < cntB) ? b3w : 0.f;
            // 8 independent gathers in flight
            f16x8 hA0 = *reinterpret_cast<const f16x8*>(Hc + (size_t)a0s * 128);
            f16x8 hA1 = *reinterpret_cast<const f16x8*>(Hc + (size_t)a1s * 128);
            f16x8 hA2 = *reinterpret_cast<const f16x8*>(Hc + (size_t)a2s * 128);
            f16x8 hA3 = *reinterpret_cast<const f16x8*>(Hc + (size_t)a3s * 128);
            f16x8 hB0 = *reinterpret_cast<const f16x8*>(Hc + (size_t)b0s * 128);
            f16x8 hB1 = *reinterpret_cast<const f16x8*>(Hc + (size_t)b1s * 128);
            f16x8 hB2 = *reinterpret_cast<const f16x8*>(Hc + (size_t)b2s * 128);
            f16x8 hB3 = *reinterpret_cast<const f16x8*>(Hc + (size_t)b3s * 128);
            #pragma unroll
            for (int q = 0; q < 8; ++q) accA[q] = fmaf(a0w, (float)hA0[q], accA[q]);
            #pragma unroll
            for (int q = 0; q < 8; ++q) accA[q] = fmaf(a1w, (float)hA1[q], accA[q]);
            #pragma unroll
            for (int q = 0; q < 8; ++q) accA[q] = fmaf(a2w, (float)hA2[q], accA[q]);
            #pragma unroll
            for (int q = 0; q < 8; ++q) accA[q] = fmaf(a3w, (float)hA3[q], accA[q]);
            #pragma unroll
            for (int q = 0; q < 8; ++q) accB[q] = fmaf(b0w, (float)hB0[q], accB[q]);
            #pragma unroll
            for (int q = 0; q < 8; ++q) accB[q] = fmaf(b1w, (float)hB1[q], accB[q]);
            #pragma unroll
            for (int q = 0; q < 8; ++q) accB[q] = fmaf(b2w, (float)hB2[q], accB[q]);
            #pragma unroll
            for (int q = 0; q < 8; ++q) accB[q] = fmaf(b3w, (float)hB3[q], accB[q]);
        }
        baseA += 64;
        baseB += 64;
    }

    // Reduce across the 4 groups for both nodes.
    #pragma unroll
    for (int q = 0; q < 8; ++q) {
        accA[q] += __shfl_xor(accA[q], 16);
        accA[q] += __shfl_xor(accA[q], 32);
        accB[q] += __shfl_xor(accB[q], 16);
        accB[q] += __shfl_xor(accB[q], 32);
    }

    float invA = (eA1 > eA0) ? (1.f / SA) : 0.f;
    float invB = (hasB && eB1 > eB0) ? (1.f / SB) : 0.f;
    if (grp == 0) {
        float4 b0 = *reinterpret_cast<const float4*>(bias + l16 * 8);
        float4 b1 = *reinterpret_cast<const float4*>(bias + l16 * 8 + 4);
        float4 o0, o1;
        o0.x = accA[0] * invA + b0.x;
        o0.y = accA[1] * invA + b0.y;
        o0.z = accA[2] * invA + b0.z;
        o0.w = accA[3] * invA + b0.w;
        o1.x = accA[4] * invA + b1.x;
        o1.y = accA[5] * invA + b1.y;
        o1.z = accA[6] * invA + b1.z;
        o1.w = accA[7] * invA + b1.w;
        *reinterpret_cast<float4*>(OUT + (size_t)nA * 128 + l16 * 8)     = o0;
        *reinterpret_cast<float4*>(OUT + (size_t)nA * 128 + l16 * 8 + 4) = o1;
        if (hasB) {
            float4 p0, p1;
            p0.x = accB[0] * invB + b0.x;
            p0.y = accB[1] * invB + b0.y;
            p0.z = accB[2] * invB + b0.z;
            p0.w = accB[3] * invB + b0.w;
            p1.x = accB[4] * invB + b1.x;
            p1.y = accB[5] * invB + b1.y;
            p1.z = accB[6] * invB + b1.z;
            p1.w = accB[7] * invB + b1.w;
            *reinterpret_cast<float4*>(OUT + (size_t)nB * 128 + l16 * 8)     = p0;
            *reinterpret_cast<float4*>(OUT + (size_t)nB * 128 + l16 * 8 + 4) = p1;
        }
    }
}

// ---------------------------------------------------------------------------
// Per-graph node ranges via binary search on sorted batch
// ---------------------------------------------------------------------------
__global__ void graph_ranges_kernel(const int* __restrict__ batch, int n_nodes,
                                    int n_graphs, int* __restrict__ gstart) {
    int g = blockIdx.x * blockDim.x + threadIdx.x;
    if (g > n_graphs) return;
    int lo = 0, hi = n_nodes;
    while (lo < hi) {
        int mid = (lo + hi) >> 1;
        if (batch[mid] < g) lo = mid + 1; else hi = mid;
    }
    gstart[g] = lo;
}

// ---------------------------------------------------------------------------
// Mean pool, stage A: 2048 blocks (16 waves/CU), disjoint chunk sums.
// ---------------------------------------------------------------------------
__global__ __launch_bounds__(128) void pool_partial_kernel(
    const float* __restrict__ X, const int* __restrict__ gstart,
    float* __restrict__ partial)
{
    int g = blockIdx.x >> 3;           // POOL_SPLIT = 8
    int split = blockIdx.x & 7;
    int c = threadIdx.x;               // 0..127
    int s = gstart[g], e = gstart[g + 1];
    int len = e - s;
    int i0 = s + (len * split) / POOL_SPLIT;
    int i1 = s + (len * (split + 1)) / POOL_SPLIT;
    float acc = 0.f;
    for (int i = i0; i < i1; ++i) acc += X[(size_t)i * 128 + c];
    partial[(size_t)blockIdx.x * 128 + c] = acc;
}

// ---------------------------------------------------------------------------
// Mean pool stage B + final linear [128 -> 8].
// ---------------------------------------------------------------------------
__global__ __launch_bounds__(128) void pool_final_kernel(
    const float* __restrict__ partial, const int* __restrict__ gstart,
    const float* __restrict__ lin_w, const float* __restrict__ lin_b,
    float* __restrict__ out)
{
    int g = blockIdx.x;
    int c = threadIdx.x;   // 0..127
    float acc = 0.f;
    #pragma unroll
    for (int sp = 0; sp < POOL_SPLIT; ++sp)
        acc += partial[(size_t)(g * POOL_SPLIT + sp) * 128 + c];
    float cnt = (float)(gstart[g + 1] - gstart[g]);
    float pooled = acc / fmaxf(cnt, 1.0f);
    __shared__ float p[128];
    p[c] = pooled;
    __syncthreads();
    if (c < 8) {
        float o = lin_b[c];
        for (int k = 0; k < 128; ++k) o += p[k] * lin_w[k * 8 + c];
        out[g * 8 + c] = o;
    }
}

// ---------------------------------------------------------------------------
extern "C" void kernel_launch(void* const* d_in, const int* in_sizes, int n_in,
                              void* d_out, int out_size, void* d_ws, size_t ws_size,
                              hipStream_t stream)
{
    const float* x     = (const float*)d_in[0];
    const int*   ei    = (const int*)d_in[1];
    // d_in[2] = edge_attr (unused)
    const int*   batch = (const int*)d_in[3];
    const float* W[3]   = {(const float*)d_in[4],  (const float*)d_in[8],  (const float*)d_in[12]};
    const float* asr[3] = {(const float*)d_in[5],  (const float*)d_in[9],  (const float*)d_in[13]};
    const float* adt[3] = {(const float*)d_in[6],  (const float*)d_in[10], (const float*)d_in[14]};
    const float* bia[3] = {(const float*)d_in[7],  (const float*)d_in[11], (const float*)d_in[15]};
    const float* lin_w = (const float*)d_in[16];
    const float* lin_b = (const float*)d_in[17];
    float* out = (float*)d_out;

    // workspace carve-up
    char* ws = (char*)d_ws;
    size_t off = 0;
    auto carve = [&](size_t bytes) {
        void* p = ws + off;
        off = (off + bytes + 255) & ~(size_t)255;
        return p;
    };
    _Float16* Hh    = (_Float16*)carve((size_t)N_NODES_C * 128 * 2);  // f16 H (gather path)
    float* bufB     = (float*)carve((size_t)N_NODES_C * 128 * 4);     // layer out / next x
    float* alpha_s  = (float*)carve((size_t)N_NODES_C * 4);
    float* alpha_d  = (float*)carve((size_t)N_NODES_C * 4);
    int*   deg      = (int*)carve((size_t)N_NODES_C * 4);
    int*   row_start= (int*)carve((size_t)(N_NODES_C + 1) * 4);
    int*   rank     = (int*)carve((size_t)N_EDGES_C * 4);
    int*   csr_src  = (int*)carve((size_t)N_EDGES_C * 4);
    int*   gstart   = (int*)carve((size_t)(N_GRAPHS_C + 1) * 4);
    int*   bsum     = (int*)carve((size_t)SCAN_NB * 4);
    float* ppart    = (float*)carve((size_t)N_GRAPHS_C * POOL_SPLIT * 128 * 4);
    _Float16* wt_h[3];
    _Float16* wt_l[3];
    wt_h[0] = (_Float16*)carve((size_t)128 * 256 * 2);
    wt_l[0] = (_Float16*)carve((size_t)128 * 256 * 2);
    wt_h[1] = (_Float16*)carve((size_t)128 * 128 * 2);
    wt_l[1] = (_Float16*)carve((size_t)128 * 128 * 2);
    wt_h[2] = (_Float16*)carve((size_t)128 * 128 * 2);
    wt_l[2] = (_Float16*)carve((size_t)128 * 128 * 2);

    const int* src = ei;             // edge_index[0]
    const int* dst = ei + N_EDGES_C; // edge_index[1]

    // --- CSR build (graph is identical across layers) + W conversion ---
    hipMemsetAsync(deg, 0, (size_t)N_NODES_C * 4, stream);
    hist_rank_kernel<<<(N_EDGES_C + 255) / 256, 256, 0, stream>>>(dst, deg, rank, N_EDGES_C);
    scan1_kernel<<<SCAN_NB, 256, 0, stream>>>(deg, bsum, N_NODES_C);
    scan2_kernel<<<1, 256, 0, stream>>>(bsum, SCAN_NB);
    scan3_kernel<<<SCAN_NB, 256, 0, stream>>>(deg, bsum, row_start, N_NODES_C);
    scatter_bucket_kernel<<<SCAT_BUCKETS * SCAT_CHUNKS, 256, 0, stream>>>(
        src, dst, rank, row_start, csr_src, N_EDGES_C);
    graph_ranges_kernel<<<2, 256, 0, stream>>>(batch, N_NODES_C, N_GRAPHS_C, gstart);
    convert_w_kernel<<<(256 * 128 + 255) / 256, 256, 0, stream>>>(W[0], wt_h[0], wt_l[0], 256);
    convert_w_kernel<<<(128 * 128 + 255) / 256, 256, 0, stream>>>(W[1], wt_h[1], wt_l[1], 128);
    convert_w_kernel<<<(128 * 128 + 255) / 256, 256, 0, stream>>>(W[2], wt_h[2], wt_l[2], 128);

    const int gemm_grid = (N_NODES_C + 63) / 64;
    const int agg_grid  = (N_NODES_C + 7) / 8;   // 2 nodes/wave, 4 waves/block

    // --- layer 0 (K=256, no input relu) ---
    gemm_mfma_kernel<IN_F_C, false><<<gemm_grid, 256, 0, stream>>>(
        x, wt_h[0], wt_l[0], asr[0], adt[0], Hh, alpha_s, alpha_d, N_NODES_C);
    aggregate_kernel<<<agg_grid, 256, 0, stream>>>(
        Hh, alpha_s, alpha_d, row_start, csr_src, bia[0], bufB, N_NODES_C);

    // --- layer 1 (K=128, relu on input) ---
    gemm_mfma_kernel<HID_C, true><<<gemm_grid, 256, 0, stream>>>(
        bufB, wt_h[1], wt_l[1], asr[1], adt[1], Hh, alpha_s, alpha_d, N_NODES_C);
    aggregate_kernel<<<agg_grid, 256, 0, stream>>>(
        Hh, alpha_s, alpha_d, row_start, csr_src, bia[1], bufB, N_NODES_C);

    // --- layer 2 (K=128, relu on input, no relu on output) ---
    gemm_mfma_kernel<HID_C, true><<<gemm_grid, 256, 0, stream>>>(
        bufB, wt_h[2], wt_l[2], asr[2], adt[2], Hh, alpha_s, alpha_d, N_NODES_C);
    aggregate_kernel<<<agg_grid, 256, 0, stream>>>(
        Hh, alpha_s, alpha_d, row_start, csr_src, bia[2], bufB, N_NODES_C);

    // --- mean pool (2-stage) + linear ---
    pool_partial_kernel<<<N_GRAPHS_C * POOL_SPLIT, 128, 0, stream>>>(bufB, gstart, ppart);
    pool_final_kernel<<<N_GRAPHS_C, 128, 0, stream>>>(ppart, gstart, lin_w, lin_b, out);
}

// Round 10
// 389.748 us; speedup vs baseline: 1.1124x; 1.0128x over previous
//
#include <hip/hip_runtime.h>
#include <cstdint>
#include <cstddef>

#define N_NODES_C  50000
#define N_EDGES_C  800000
#define IN_F_C     256
#define HID_C      128
#define N_GRAPHS_C 256
#define NEG_SLOPE_C 0.2f
#define SCAN_NB    ((N_NODES_C + 255) / 256)   // 196 blocks
#define POOL_SPLIT 8
#define SCAT_BUCKETS 8
#define SCAT_CHUNKS  256

typedef _Float16 f16x8 __attribute__((ext_vector_type(8)));
typedef float    f32x4 __attribute__((ext_vector_type(4)));

// ---------------------------------------------------------------------------
// CSR build: histogram (+per-edge rank) -> hierarchical scan -> atomic-free
// bucketed scatter.
// ---------------------------------------------------------------------------
__global__ void hist_rank_kernel(const int* __restrict__ dst, int* __restrict__ deg,
                                 int* __restrict__ rank, int E) {
    int e = blockIdx.x * blockDim.x + threadIdx.x;
    if (e < E) rank[e] = atomicAdd(&deg[dst[e]], 1);
}

// Per-block sums of deg (coalesced), 256 elems/block.
__global__ __launch_bounds__(256) void scan1_kernel(const int* __restrict__ deg,
                                                    int* __restrict__ bsum, int n) {
    int i = blockIdx.x * 256 + threadIdx.x;
    int lane = threadIdx.x & 63;
    int w = threadIdx.x >> 6;
    int v = (i < n) ? deg[i] : 0;
    #pragma unroll
    for (int off = 32; off >= 1; off >>= 1) v += __shfl_xor(v, off);
    __shared__ int ws_[4];
    if (lane == 0) ws_[w] = v;
    __syncthreads();
    if (threadIdx.x == 0) bsum[blockIdx.x] = ws_[0] + ws_[1] + ws_[2] + ws_[3];
}

// Exclusive scan of the block sums (nb <= 256), single block.
__global__ __launch_bounds__(256) void scan2_kernel(int* __restrict__ bsum, int nb) {
    int t = threadIdx.x;
    int lane = t & 63;
    int w = t >> 6;
    int orig = (t < nb) ? bsum[t] : 0;
    int v = orig;
    #pragma unroll
    for (int off = 1; off < 64; off <<= 1) {
        int u = __shfl_up(v, off);
        if (lane >= off) v += u;
    }
    __shared__ int wsum[4];
    if (lane == 63) wsum[w] = v;
    __syncthreads();
    int add = 0;
    for (int i = 0; i < w; ++i) add += wsum[i];
    if (t < nb) bsum[t] = v + add - orig;   // exclusive prefix
}

// Block-local exclusive scan + block offset -> row_start.
__global__ __launch_bounds__(256) void scan3_kernel(const int* __restrict__ deg,
                                                    const int* __restrict__ boff,
                                                    int* __restrict__ row_start, int n) {
    int i = blockIdx.x * 256 + threadIdx.x;
    int lane = threadIdx.x & 63;
    int w = threadIdx.x >> 6;
    int d = (i < n) ? deg[i] : 0;
    int v = d;
    #pragma unroll
    for (int off = 1; off < 64; off <<= 1) {
        int u = __shfl_up(v, off);
        if (lane >= off) v += u;
    }
    __shared__ int wsum[4];
    if (lane == 63) wsum[w] = v;
    __syncthreads();
    int add = boff[blockIdx.x];
    for (int k = 0; k < w; ++k) add += wsum[k];
    int excl = v - d + add;
    if (i < n) {
        row_start[i] = excl;
        if (i == n - 1) row_start[n] = excl + d;
    }
}

// Atomic-free bucketed scatter (bucket rides round-robin block->XCD mapping).
__global__ __launch_bounds__(256) void scatter_bucket_kernel(
    const int* __restrict__ src, const int* __restrict__ dst,
    const int* __restrict__ rank, const int* __restrict__ row_start,
    int* __restrict__ csr_src, int E)
{
    const int bucket = blockIdx.x & (SCAT_BUCKETS - 1);
    const int chunk  = blockIdx.x / SCAT_BUCKETS;
    constexpr int NPB = (N_NODES_C + SCAT_BUCKETS - 1) / SCAT_BUCKETS;  // 6250
    const int lo = bucket * NPB;
    const int hi = min(lo + NPB, N_NODES_C);
    const int per = (E + SCAT_CHUNKS - 1) / SCAT_CHUNKS;
    const int e0 = chunk * per;
    const int e1 = min(e0 + per, E);
    for (int e = e0 + (int)threadIdx.x; e < e1; e += 256) {
        int d = dst[e];
        if (d >= lo && d < hi) {
            csr_src[row_start[d] + rank[e]] = src[e];
        }
    }
}

// ---------------------------------------------------------------------------
// One-time W conversion: W[K][128] fp32 -> WT_hi/WT_lo [128][K] f16 (Markidis
// split). Transposed so B fragments read 8 contiguous k-values per lane.
// ---------------------------------------------------------------------------
__global__ void convert_w_kernel(const float* __restrict__ W,
                                 _Float16* __restrict__ wt_hi,
                                 _Float16* __restrict__ wt_lo, int K) {
    int id = blockIdx.x * 256 + threadIdx.x;
    if (id >= K * 128) return;
    int c = id & 127;
    int k = id >> 7;
    float w = W[(size_t)k * 128 + c];
    _Float16 h = (_Float16)w;
    _Float16 l = (_Float16)(w - (float)h);
    wt_hi[(size_t)c * K + k] = h;
    wt_lo[(size_t)c * K + k] = l;
}

// ---------------------------------------------------------------------------
// MFMA GEMM: H[n,128] = act(X)[n,K] @ W[K,128], f16 split (hi*hi+hi*lo+lo*hi),
// mfma_f32_16x16x32_f16. H written f16-only (gather path). Fused alpha dots.
// ---------------------------------------------------------------------------
template <int K, bool RELU>
__global__ __launch_bounds__(256) void gemm_mfma_kernel(
    const float* __restrict__ X,
    const _Float16* __restrict__ WTh, const _Float16* __restrict__ WTl,
    const float* __restrict__ a_src, const float* __restrict__ a_dst,
    _Float16* __restrict__ Hh, float* __restrict__ alpha_s, float* __restrict__ alpha_d,
    int n_rows)
{
    constexpr int NS = K / 32;
    __shared__ _Float16 XsH[2][64 * 32];   // 2 x 4 KiB
    __shared__ _Float16 XsL[2][64 * 32];   // 2 x 4 KiB
    __shared__ float aps[4][64];           // 1 KiB
    __shared__ float apd[4][64];           // 1 KiB

    const int t = threadIdx.x;
    const int row0 = blockIdx.x * 64;
    const int lane = t & 63;
    const int wv = t >> 6;        // wave id 0..3
    const int l15 = lane & 15;
    const int l4 = lane >> 4;     // 0..3
    const int wcol = wv * 32;

    const int sr = t >> 2;        // 0..63
    const int skg = t & 3;        // 0..3
    const int sgrow = row0 + sr;
    const int sslot = skg ^ (sr & 3);
    const int sldsoff = sr * 32 + sslot * 8;
    const bool srow_ok = (sgrow < n_rows);
    const float* __restrict__ srowp = X + (size_t)sgrow * K + skg * 8;

    f32x4 acc[4][2];
    #pragma unroll
    for (int mt = 0; mt < 4; ++mt)
        #pragma unroll
        for (int nt = 0; nt < 2; ++nt)
            acc[mt][nt] = (f32x4){0.f, 0.f, 0.f, 0.f};

    // --- prologue: stage step 0 ---
    {
        float4 xa = make_float4(0.f, 0.f, 0.f, 0.f), xb = xa;
        if (srow_ok) {
            xa = *reinterpret_cast<const float4*>(srowp);
            xb = *reinterpret_cast<const float4*>(srowp + 4);
        }
        float v[8] = {xa.x, xa.y, xa.z, xa.w, xb.x, xb.y, xb.z, xb.w};
        f16x8 hi, lo;
        #pragma unroll
        for (int i = 0; i < 8; ++i) {
            float x = v[i];
            if (RELU) x = fmaxf(x, 0.f);
            _Float16 h = (_Float16)x;
            hi[i] = h;
            lo[i] = (_Float16)(x - (float)h);
        }
        *reinterpret_cast<f16x8*>(&XsH[0][sldsoff]) = hi;
        *reinterpret_cast<f16x8*>(&XsL[0][sldsoff]) = lo;
    }
    __syncthreads();

    int cur = 0;
    for (int step = 0; step < NS; ++step) {
        const int k0 = step * 32;
        float4 nxa = make_float4(0.f, 0.f, 0.f, 0.f), nxb = nxa;
        const bool hasNext = (step + 1 < NS);
        if (hasNext && srow_ok) {
            nxa = *reinterpret_cast<const float4*>(srowp + k0 + 32);
            nxb = *reinterpret_cast<const float4*>(srowp + k0 + 36);
        }
        f16x8 bh[2], bl[2];
        #pragma unroll
        for (int nt = 0; nt < 2; ++nt) {
            const size_t bo = (size_t)(wcol + nt * 16 + l15) * K + k0 + l4 * 8;
            bh[nt] = *reinterpret_cast<const f16x8*>(WTh + bo);
            bl[nt] = *reinterpret_cast<const f16x8*>(WTl + bo);
        }
        const int aslot = l4 ^ (l15 & 3);
        f16x8 ah[4], al[4];
        #pragma unroll
        for (int mt = 0; mt < 4; ++mt) {
            const int off = (mt * 16 + l15) * 32 + aslot * 8;
            ah[mt] = *reinterpret_cast<const f16x8*>(&XsH[cur][off]);
            al[mt] = *reinterpret_cast<const f16x8*>(&XsL[cur][off]);
        }
        #pragma unroll
        for (int mt = 0; mt < 4; ++mt)
            #pragma unroll
            for (int nt = 0; nt < 2; ++nt) {
                acc[mt][nt] = __builtin_amdgcn_mfma_f32_16x16x32_f16(ah[mt], bh[nt], acc[mt][nt], 0, 0, 0);
                acc[mt][nt] = __builtin_amdgcn_mfma_f32_16x16x32_f16(ah[mt], bl[nt], acc[mt][nt], 0, 0, 0);
                acc[mt][nt] = __builtin_amdgcn_mfma_f32_16x16x32_f16(al[mt], bh[nt], acc[mt][nt], 0, 0, 0);
            }
        if (hasNext) {
            float v[8] = {nxa.x, nxa.y, nxa.z, nxa.w, nxb.x, nxb.y, nxb.z, nxb.w};
            f16x8 hi, lo;
            #pragma unroll
            for (int i = 0; i < 8; ++i) {
                float x = v[i];
                if (RELU) x = fmaxf(x, 0.f);
                _Float16 h = (_Float16)x;
                hi[i] = h;
                lo[i] = (_Float16)(x - (float)h);
            }
            *reinterpret_cast<f16x8*>(&XsH[cur ^ 1][sldsoff]) = hi;
            *reinterpret_cast<f16x8*>(&XsL[cur ^ 1][sldsoff]) = lo;
        }
        __syncthreads();
        cur ^= 1;
    }

    // --- epilogue: f16 H stores + fused alpha dots (f32) ---
    const float as0 = a_src[wcol + l15];
    const float as1 = a_src[wcol + 16 + l15];
    const float ad0 = a_dst[wcol + l15];
    const float ad1 = a_dst[wcol + 16 + l15];

    #pragma unroll
    for (int mt = 0; mt < 4; ++mt) {
        #pragma unroll
        for (int reg = 0; reg < 4; ++reg) {
            const int lrow = mt * 16 + l4 * 4 + reg;
            const int grow = row0 + lrow;
            if (grow < n_rows) {
                Hh[(size_t)grow * 128 + wcol + l15]      = (_Float16)acc[mt][0][reg];
                Hh[(size_t)grow * 128 + wcol + 16 + l15] = (_Float16)acc[mt][1][reg];
            }
            float s = acc[mt][0][reg] * as0 + acc[mt][1][reg] * as1;
            float d = acc[mt][0][reg] * ad0 + acc[mt][1][reg] * ad1;
            #pragma unroll
            for (int off = 8; off >= 1; off >>= 1) {
                s += __shfl_xor(s, off);
                d += __shfl_xor(d, off);
            }
            if (l15 == 0) {
                aps[wv][lrow] = s;
                apd[wv][lrow] = d;
            }
        }
    }
    __syncthreads();
    if (t < 64) {
        const int grow = row0 + t;
        if (grow < n_rows)
            alpha_s[grow] = aps[0][t] + aps[1][t] + aps[2][t] + aps[3][t];
    } else if (t < 128) {
        const int tt = t - 64;
        const int grow = row0 + tt;
        if (grow < n_rows)
            alpha_d[grow] = apd[0][tt] + apd[1][tt] + apd[2][tt] + apd[3][tt];
    }
}

// ---------------------------------------------------------------------------
// Per-dst-node softmax + weighted aggregation, v6: union-range 2 nodes/wave.
// v4 serviced 2 x ceil(max(degA,degB)/16) x 16 slots per pair (~40% dead for
// Poisson(16) degrees). Rows are CSR-contiguous, so [eA0,eA1)+[eA1,eB1) is
// ONE range: process it as a single 32-slot/iter stream (group owns 8
// contiguous slots -> still 8 gathers in flight/lane), slots ~ ceil(sum/32)
// (~25% fewer). Per-slot A/B routing is a group-uniform branch (the split
// crosses one group per iteration).
// ---------------------------------------------------------------------------
__global__ __launch_bounds__(256) void aggregate_kernel(
    const _Float16* __restrict__ Hh, const float* __restrict__ alpha_s,
    const float* __restrict__ alpha_d, const int* __restrict__ row_start,
    const int* __restrict__ csr_src, const float* __restrict__ bias,
    float* __restrict__ OUT, int n_nodes)
{
    int wvid = (blockIdx.x * blockDim.x + threadIdx.x) >> 6;
    int lane = threadIdx.x & 63;
    int nA = wvid * 2;
    int nB = nA + 1;
    if (nA >= n_nodes) return;
    const bool hasB = (nB < n_nodes);

    const int e0 = row_start[nA];
    const int eSplit = row_start[nA + 1];
    const int e1 = hasB ? row_start[nB + 1] : eSplit;
    const float adA = alpha_d[nA];
    const float adB = hasB ? alpha_d[nB] : 0.f;

    const int grp = lane >> 4;           // group 0..3, owns slots grp*8..grp*8+7
    const int l16 = lane & 15;           // col block: cols 8*l16 .. 8*l16+7
    const _Float16* __restrict__ Hc = Hh + l16 * 8;

    float SA = 0.f, SB = 0.f;
    float accA[8], accB[8];
    #pragma unroll
    for (int q = 0; q < 8; ++q) { accA[q] = 0.f; accB[q] = 0.f; }

    for (int base = e0; base < e1; base += 64) {
        const int cnt = min(64, e1 - base);
        float w = 0.f;
        int s = 0;
        const bool laneA = (base + lane) < eSplit;
        if (lane < cnt) {
            s = csr_src[base + lane];
            float z = alpha_s[s] + (laneA ? adA : adB);
            z = (z >= 0.f) ? z : NEG_SLOPE_C * z;
            w = __expf(z);
        }
        // two masked reductions (lanes >= cnt already have w = 0)
        float wa = laneA ? w : 0.f;
        float wb = w - wa;
        #pragma unroll
        for (int off = 32; off >= 1; off >>= 1) {
            wa += __shfl_xor(wa, off);
            wb += __shfl_xor(wb, off);
        }
        SA += wa;
        SB += wb;

        // union gather: 32 slots/iter; group owns 8 contiguous slots.
        for (int jj = 0; jj < cnt; jj += 32) {
            const int s0 = jj + grp * 8;      // group's first slot
            float bw[8];
            int bs[8];
            #pragma unroll
            for (int t = 0; t < 8; ++t) {
                const int idx = s0 + t;
                float ww = __shfl(w, idx & 63);
                int ss = __shfl(s, idx & 63);
                bw[t] = (idx < cnt) ? ww : 0.f;
                bs[t] = ss;
            }
            // 8 independent gathers in flight
            f16x8 h0 = *reinterpret_cast<const f16x8*>(Hc + (size_t)bs[0] * 128);
            f16x8 h1 = *reinterpret_cast<const f16x8*>(Hc + (size_t)bs[1] * 128);
            f16x8 h2 = *reinterpret_cast<const f16x8*>(Hc + (size_t)bs[2] * 128);
            f16x8 h3 = *reinterpret_cast<const f16x8*>(Hc + (size_t)bs[3] * 128);
            f16x8 h4 = *reinterpret_cast<const f16x8*>(Hc + (size_t)bs[4] * 128);
            f16x8 h5 = *reinterpret_cast<const f16x8*>(Hc + (size_t)bs[5] * 128);
            f16x8 h6 = *reinterpret_cast<const f16x8*>(Hc + (size_t)bs[6] * 128);
            f16x8 h7 = *reinterpret_cast<const f16x8*>(Hc + (size_t)bs[7] * 128);
            // route each slot to accA or accB (group-uniform branch; the A/B
            // split crosses at most one group per iteration)
            const int bnd = eSplit - base;    // slots < bnd are A-edges
            #define AGG_SLOT(T, HV)                                              \
                if (s0 + (T) < bnd) {                                            \
                    _Pragma("unroll")                                            \
                    for (int q = 0; q < 8; ++q)                                  \
                        accA[q] = fmaf(bw[T], (float)HV[q], accA[q]);            \
                } else {                                                         \
                    _Pragma("unroll")                                            \
                    for (int q = 0; q < 8; ++q)                                  \
                        accB[q] = fmaf(bw[T], (float)HV[q], accB[q]);            \
                }
            AGG_SLOT(0, h0)
            AGG_SLOT(1, h1)
            AGG_SLOT(2, h2)
            AGG_SLOT(3, h3)
            AGG_SLOT(4, h4)
            AGG_SLOT(5, h5)
            AGG_SLOT(6, h6)
            AGG_SLOT(7, h7)
            #undef AGG_SLOT
        }
    }

    // Reduce across the 4 groups for both nodes.
    #pragma unroll
    for (int q = 0; q < 8; ++q) {
        accA[q] += __shfl_xor(accA[q], 16);
        accA[q] += __shfl_xor(accA[q], 32);
        accB[q] += __shfl_xor(accB[q], 16);
        accB[q] += __shfl_xor(accB[q], 32);
    }

    float invA = (eSplit > e0) ? (1.f / SA) : 0.f;
    float invB = (hasB && e1 > eSplit) ? (1.f / SB) : 0.f;
    if (grp == 0) {
        float4 b0 = *reinterpret_cast<const float4*>(bias + l16 * 8);
        float4 b1 = *reinterpret_cast<const float4*>(bias + l16 * 8 + 4);
        float4 o0, o1;
        o0.x = accA[0] * invA + b0.x;
        o0.y = accA[1] * invA + b0.y;
        o0.z = accA[2] * invA + b0.z;
        o0.w = accA[3] * invA + b0.w;
        o1.x = accA[4] * invA + b1.x;
        o1.y = accA[5] * invA + b1.y;
        o1.z = accA[6] * invA + b1.z;
        o1.w = accA[7] * invA + b1.w;
        *reinterpret_cast<float4*>(OUT + (size_t)nA * 128 + l16 * 8)     = o0;
        *reinterpret_cast<float4*>(OUT + (size_t)nA * 128 + l16 * 8 + 4) = o1;
        if (hasB) {
            float4 p0, p1;
            p0.x = accB[0] * invB + b0.x;
            p0.y = accB[1] * invB + b0.y;
            p0.z = accB[2] * invB + b0.z;
            p0.w = accB[3] * invB + b0.w;
            p1.x = accB[4] * invB + b1.x;
            p1.y = accB[5] * invB + b1.y;
            p1.z = accB[6] * invB + b1.z;
            p1.w = accB[7] * invB + b1.w;
            *reinterpret_cast<float4*>(OUT + (size_t)nB * 128 + l16 * 8)     = p0;
            *reinterpret_cast<float4*>(OUT + (size_t)nB * 128 + l16 * 8 + 4) = p1;
        }
    }
}

// ---------------------------------------------------------------------------
// Per-graph node ranges via binary search on sorted batch
// ---------------------------------------------------------------------------
__global__ void graph_ranges_kernel(const int* __restrict__ batch, int n_nodes,
                                    int n_graphs, int* __restrict__ gstart) {
    int g = blockIdx.x * blockDim.x + threadIdx.x;
    if (g > n_graphs) return;
    int lo = 0, hi = n_nodes;
    while (lo < hi) {
        int mid = (lo + hi) >> 1;
        if (batch[mid] < g) lo = mid + 1; else hi = mid;
    }
    gstart[g] = lo;
}

// ---------------------------------------------------------------------------
// Mean pool, stage A: 2048 blocks (16 waves/CU), disjoint chunk sums.
// ---------------------------------------------------------------------------
__global__ __launch_bounds__(128) void pool_partial_kernel(
    const float* __restrict__ X, const int* __restrict__ gstart,
    float* __restrict__ partial)
{
    int g = blockIdx.x >> 3;           // POOL_SPLIT = 8
    int split = blockIdx.x & 7;
    int c = threadIdx.x;               // 0..127
    int s = gstart[g], e = gstart[g + 1];
    int len = e - s;
    int i0 = s + (len * split) / POOL_SPLIT;
    int i1 = s + (len * (split + 1)) / POOL_SPLIT;
    float acc = 0.f;
    for (int i = i0; i < i1; ++i) acc += X[(size_t)i * 128 + c];
    partial[(size_t)blockIdx.x * 128 + c] = acc;
}

// ---------------------------------------------------------------------------
// Mean pool stage B + final linear [128 -> 8].
// ---------------------------------------------------------------------------
__global__ __launch_bounds__(128) void pool_final_kernel(
    const float* __restrict__ partial, const int* __restrict__ gstart,
    const float* __restrict__ lin_w, const float* __restrict__ lin_b,
    float* __restrict__ out)
{
    int g = blockIdx.x;
    int c = threadIdx.x;   // 0..127
    float acc = 0.f;
    #pragma unroll
    for (int sp = 0; sp < POOL_SPLIT; ++sp)
        acc += partial[(size_t)(g * POOL_SPLIT + sp) * 128 + c];
    float cnt = (float)(gstart[g + 1] - gstart[g]);
    float pooled = acc / fmaxf(cnt, 1.0f);
    __shared__ float p[128];
    p[c] = pooled;
    __syncthreads();
    if (c < 8) {
        float o = lin_b[c];
        for (int k = 0; k < 128; ++k) o += p[k] * lin_w[k * 8 + c];
        out[g * 8 + c] = o;
    }
}

// ---------------------------------------------------------------------------
extern "C" void kernel_launch(void* const* d_in, const int* in_sizes, int n_in,
                              void* d_out, int out_size, void* d_ws, size_t ws_size,
                              hipStream_t stream)
{
    const float* x     = (const float*)d_in[0];
    const int*   ei    = (const int*)d_in[1];
    // d_in[2] = edge_attr (unused)
    const int*   batch = (const int*)d_in[3];
    const float* W[3]   = {(const float*)d_in[4],  (const float*)d_in[8],  (const float*)d_in[12]};
    const float* asr[3] = {(const float*)d_in[5],  (const float*)d_in[9],  (const float*)d_in[13]};
    const float* adt[3] = {(const float*)d_in[6],  (const float*)d_in[10], (const float*)d_in[14]};
    const float* bia[3] = {(const float*)d_in[7],  (const float*)d_in[11], (const float*)d_in[15]};
    const float* lin_w = (const float*)d_in[16];
    const float* lin_b = (const float*)d_in[17];
    float* out = (float*)d_out;

    // workspace carve-up
    char* ws = (char*)d_ws;
    size_t off = 0;
    auto carve = [&](size_t bytes) {
        void* p = ws + off;
        off = (off + bytes + 255) & ~(size_t)255;
        return p;
    };
    _Float16* Hh    = (_Float16*)carve((size_t)N_NODES_C * 128 * 2);  // f16 H (gather path)
    float* bufB     = (float*)carve((size_t)N_NODES_C * 128 * 4);     // layer out / next x
    float* alpha_s  = (float*)carve((size_t)N_NODES_C * 4);
    float* alpha_d  = (float*)carve((size_t)N_NODES_C * 4);
    int*   deg      = (int*)carve((size_t)N_NODES_C * 4);
    int*   row_start= (int*)carve((size_t)(N_NODES_C + 1) * 4);
    int*   rank     = (int*)carve((size_t)N_EDGES_C * 4);
    int*   csr_src  = (int*)carve((size_t)N_EDGES_C * 4);
    int*   gstart   = (int*)carve((size_t)(N_GRAPHS_C + 1) * 4);
    int*   bsum     = (int*)carve((size_t)SCAN_NB * 4);
    float* ppart    = (float*)carve((size_t)N_GRAPHS_C * POOL_SPLIT * 128 * 4);
    _Float16* wt_h[3];
    _Float16* wt_l[3];
    wt_h[0] = (_Float16*)carve((size_t)128 * 256 * 2);
    wt_l[0] = (_Float16*)carve((size_t)128 * 256 * 2);
    wt_h[1] = (_Float16*)carve((size_t)128 * 128 * 2);
    wt_l[1] = (_Float16*)carve((size_t)128 * 128 * 2);
    wt_h[2] = (_Float16*)carve((size_t)128 * 128 * 2);
    wt_l[2] = (_Float16*)carve((size_t)128 * 128 * 2);

    const int* src = ei;             // edge_index[0]
    const int* dst = ei + N_EDGES_C; // edge_index[1]

    // --- CSR build (graph is identical across layers) + W conversion ---
    hipMemsetAsync(deg, 0, (size_t)N_NODES_C * 4, stream);
    hist_rank_kernel<<<(N_EDGES_C + 255) / 256, 256, 0, stream>>>(dst, deg, rank, N_EDGES_C);
    scan1_kernel<<<SCAN_NB, 256, 0, stream>>>(deg, bsum, N_NODES_C);
    scan2_kernel<<<1, 256, 0, stream>>>(bsum, SCAN_NB);
    scan3_kernel<<<SCAN_NB, 256, 0, stream>>>(deg, bsum, row_start, N_NODES_C);
    scatter_bucket_kernel<<<SCAT_BUCKETS * SCAT_CHUNKS, 256, 0, stream>>>(
        src, dst, rank, row_start, csr_src, N_EDGES_C);
    graph_ranges_kernel<<<2, 256, 0, stream>>>(batch, N_NODES_C, N_GRAPHS_C, gstart);
    convert_w_kernel<<<(256 * 128 + 255) / 256, 256, 0, stream>>>(W[0], wt_h[0], wt_l[0], 256);
    convert_w_kernel<<<(128 * 128 + 255) / 256, 256, 0, stream>>>(W[1], wt_h[1], wt_l[1], 128);
    convert_w_kernel<<<(128 * 128 + 255) / 256, 256, 0, stream>>>(W[2], wt_h[2], wt_l[2], 128);

    const int gemm_grid = (N_NODES_C + 63) / 64;
    const int agg_grid  = (N_NODES_C + 7) / 8;   // 2 nodes/wave, 4 waves/block

    // --- layer 0 (K=256, no input relu) ---
    gemm_mfma_kernel<IN_F_C, false><<<gemm_grid, 256, 0, stream>>>(
        x, wt_h[0], wt_l[0], asr[0], adt[0], Hh, alpha_s, alpha_d, N_NODES_C);
    aggregate_kernel<<<agg_grid, 256, 0, stream>>>(
        Hh, alpha_s, alpha_d, row_start, csr_src, bia[0], bufB, N_NODES_C);

    // --- layer 1 (K=128, relu on input) ---
    gemm_mfma_kernel<HID_C, true><<<gemm_grid, 256, 0, stream>>>(
        bufB, wt_h[1], wt_l[1], asr[1], adt[1], Hh, alpha_s, alpha_d, N_NODES_C);
    aggregate_kernel<<<agg_grid, 256, 0, stream>>>(
        Hh, alpha_s, alpha_d, row_start, csr_src, bia[1], bufB, N_NODES_C);

    // --- layer 2 (K=128, relu on input, no relu on output) ---
    gemm_mfma_kernel<HID_C, true><<<gemm_grid, 256, 0, stream>>>(
        bufB, wt_h[2], wt_l[2], asr[2], adt[2], Hh, alpha_s, alpha_d, N_NODES_C);
    aggregate_kernel<<<agg_grid, 256, 0, stream>>>(
        Hh, alpha_s, alpha_d, row_start, csr_src, bia[2], bufB, N_NODES_C);

    // --- mean pool (2-stage) + linear ---
    pool_partial_kernel<<<N_GRAPHS_C * POOL_SPLIT, 128, 0, stream>>>(bufB, gstart, ppart);
    pool_final_kernel<<<N_GRAPHS_C, 128, 0, stream>>>(ppart, gstart, lin_w, lin_b, out);
}